// Round 14
// baseline (332.948 us; speedup 1.0000x reference)
//
#include <hip/hip_runtime.h>
#include <hip/hip_bf16.h>

typedef __attribute__((ext_vector_type(8))) short bf16x8;
typedef __attribute__((ext_vector_type(4))) short bf16x4;
typedef __attribute__((ext_vector_type(4))) float f32x4;

__device__ __forceinline__ short f2bf(float f){
  __hip_bfloat16 h = __float2bfloat16(f);
  return __builtin_bit_cast(short, h);
}
__device__ __forceinline__ float bf2f(short s){
  unsigned u = ((unsigned)(unsigned short)s) << 16;
  return __builtin_bit_cast(float, u);
}

__device__ __forceinline__ void gload_lds16(const short* g, char* l){
  __builtin_amdgcn_global_load_lds(
      (const __attribute__((address_space(1))) void*)g,
      (__attribute__((address_space(3))) void*)l, 16, 0, 0);
}

#define SB0() __builtin_amdgcn_sched_barrier(0)

// ---------------- GroupNorm stats ----------------
__global__ __launch_bounds__(256) void gn_stats(const float* __restrict__ x,
                                                float* __restrict__ stats){
  int b = blockIdx.x >> 5, g = blockIdx.x & 31;
  const float4* p = (const float4*)(x + ((long long)b*512 + g*16)*4096);
  float s = 0.f, s2 = 0.f;
  for (int i = threadIdx.x; i < 16384; i += 256){
    float4 v = p[i];
    s  += v.x + v.y + v.z + v.w;
    s2 += v.x*v.x + v.y*v.y + v.z*v.z + v.w*v.w;
  }
  #pragma unroll
  for (int o = 32; o; o >>= 1){ s += __shfl_xor(s, o); s2 += __shfl_xor(s2, o); }
  __shared__ float rs[4], rs2[4];
  int wid = threadIdx.x >> 6;
  if ((threadIdx.x & 63) == 0){ rs[wid] = s; rs2[wid] = s2; }
  __syncthreads();
  if (threadIdx.x == 0){
    float S  = rs[0]+rs[1]+rs[2]+rs[3];
    float S2 = rs2[0]+rs2[1]+rs2[2]+rs2[3];
    float mean = S * (1.f/65536.f);
    float var  = S2 * (1.f/65536.f) - mean*mean;
    stats[blockIdx.x*2]   = mean;
    stats[blockIdx.x*2+1] = rsqrtf(var + 1e-6f);
  }
}

// ------------- GN apply + transpose -> h bf16 [B,N,C] ------------------
__global__ __launch_bounds__(256) void gn_apply(const float* __restrict__ x,
                                                const float* __restrict__ stats,
                                                const float* __restrict__ gw,
                                                const float* __restrict__ gb,
                                                short* __restrict__ h){
  __shared__ float tile[128][65];
  int b  = blockIdx.y;
  int n0 = blockIdx.x * 64;
  int t  = threadIdx.x;
  const float* xb = x + (long long)b*512*4096;
  for (int cc = 0; cc < 4; cc++){
    int c0 = cc*128;
    #pragma unroll
    for (int r = 0; r < 128; r += 4){
      int c = r + (t >> 6);
      tile[c][t & 63] = xb[(long long)(c0+c)*4096 + n0 + (t & 63)];
    }
    __syncthreads();
    int n = t >> 2, cp = (t & 3)*32;
    short tmp[32];
    #pragma unroll
    for (int j = 0; j < 32; j++){
      int c = c0 + cp + j;
      float mean = stats[(b*32 + (c >> 4))*2];
      float rstd = stats[(b*32 + (c >> 4))*2 + 1];
      float v = (tile[cp+j][n] - mean)*rstd*gw[c] + gb[c];
      tmp[j] = f2bf(v);
    }
    long long ho = ((long long)b*4096 + n0 + n)*512 + c0 + cp;
    #pragma unroll
    for (int j2 = 0; j2 < 4; j2++){
      bf16x8 v8;
      #pragma unroll
      for (int e = 0; e < 8; e++) v8[e] = tmp[j2*8 + e];
      *(bf16x8*)&h[ho + j2*8] = v8;
    }
    __syncthreads();
  }
}

// ---------- fp32 -> bf16 weights (wq/wk/wv land contiguously = wqkv) ----------
__global__ __launch_bounds__(256) void f2bf_all(
    const float* __restrict__ w0, const float* __restrict__ w1,
    const float* __restrict__ w2, const float* __restrict__ w3,
    short* __restrict__ o0, short* __restrict__ o1,
    short* __restrict__ o2, short* __restrict__ o3){
  int idx = blockIdx.x*256 + threadIdx.x;
  int m = idx >> 15, r = idx & 32767;
  const float* src = (m==0) ? w0 : (m==1) ? w1 : (m==2) ? w2 : w3;
  short* dst       = (m==0) ? o0 : (m==1) ? o1 : (m==2) ? o2 : o3;
  const float4* p = (const float4*)src + (long long)r*2;
  float4 a = p[0], c = p[1];
  bf16x8 v;
  v[0]=f2bf(a.x); v[1]=f2bf(a.y); v[2]=f2bf(a.z); v[3]=f2bf(a.w);
  v[4]=f2bf(c.x); v[5]=f2bf(c.y); v[6]=f2bf(c.z); v[7]=f2bf(c.w);
  *(bf16x8*)&dst[(long long)r*8] = v;
}

// ---------------- concat q/k/v biases ----------------
__global__ __launch_bounds__(256) void bcat(const float* __restrict__ bq,
                                            const float* __restrict__ bk,
                                            const float* __restrict__ bv,
                                            float* __restrict__ o){
  int t = blockIdx.x*256 + threadIdx.x;
  if (t < 512){ o[t] = bq[t]; o[512+t] = bk[t]; o[1024+t] = bv[t]; }
}

// ---------------- denominator reduce ----------------
__global__ __launch_bounds__(256) void reduce_den(const float* __restrict__ partial,
                                                  float* __restrict__ inv_den,
                                                  int nrows){
  int r = blockIdx.x*256 + threadIdx.x;
  if (r >= nrows) return;
  const float4* p = (const float4*)(partial + (long long)r*16);
  float4 a = p[0], b = p[1], c = p[2], d = p[3];
  float s = a.x+a.y+a.z+a.w + b.x+b.y+b.z+b.w + c.x+c.y+c.z+c.w + d.x+d.y+d.z+d.w;
  inv_den[r] = 1.f / s;
}

// ====== persistent 8-phase 256x256 scores kernel (4 tiles per block) =========
// Grid 256 (1 block/CU). Each block runs 4 tiles of its XCD region. Next
// tile's 12 prologue DMAs issue BEFORE the current epilogue (DMA overlaps
// exp/store VALU); epilogue uses lgkm0 + raw barrier (no vmcnt drain).
// rowpart scratch lives past the two 64KB buffers (LDS = 132 KB).
__global__ __launch_bounds__(512, 2) void gemm8p(
    const short* __restrict__ A, const short* __restrict__ Bw,
    short* __restrict__ outp,
    int Nn, int Kd,
    long long sA, long long sB, long long sO,
    float* __restrict__ partial)
{
  constexpr int BUFSZ = 65536;
  extern __shared__ char smem[];
  float* rowpart = (float*)(smem + 131072);

  // block -> (region, by-offset q); tiles j=0..3 -> o = q*4+j (bx varies)
  int id = blockIdx.x;
  int xcd = id & 7, s2 = id >> 3;            // s2 0..31
  int region = xcd + ((s2 >> 2) << 3);       // 0..63
  int q = s2 & 3;
  const int bz = region >> 4;

  const int t = threadIdx.x;
  const int lane = t & 63, wid = t >> 6;
  const int g = lane >> 4, lr = lane & 15;
  const int wr = wid >> 2, wc = wid & 3;
  const long long KdLL = Kd;

  // current tile staging state
  const short* Ab; const short* Bb; int m0, n0;
  auto SETTILE = [&](int j){
    int o = q*4 + j;
    int bx = (region & 3)*4 + (o & 3);
    int by = ((region >> 2) & 3)*4 + (o >> 2);
    m0 = bx*256; n0 = by*256;
    Ab = A + bz*sA; Bb = Bw + bz*sB;
  };

  auto STG = [&](int kt, int buf, int which){
    const bool isB = which >= 2;
    const int h = which & 1;
    char* d = smem + buf*BUFSZ + (isB ? 32768 : 0) + h*16384 + t*16;
    const short* src = isB ? Bb : Ab;
    const int base = isB ? n0 : m0;
    #pragma unroll
    for (int p = 0; p < 2; p++){
      int row = h*128 + p*64 + (t >> 3);
      int ch = t & 7;
      gload_lds16(src + (long long)(base+row)*KdLL + (long long)kt*64 + ((ch ^ (row&7))*8),
                  d + p*8192);
    }
  };

  int roA[8], swA[8], roB[4], swB[4];
  #pragma unroll
  for (int mf = 0; mf < 8; mf++){
    int ra = wr*128 + mf*16 + lr;
    roA[mf] = ra*128; swA[mf] = ra & 7;
  }
  #pragma unroll
  for (int nf = 0; nf < 4; nf++){
    int rb = wc*64 + nf*16 + lr;
    roB[nf] = 32768 + rb*128; swB[nf] = rb & 7;
  }

  f32x4 acc[8][4];
  #pragma unroll
  for (int i = 0; i < 8; i++)
    #pragma unroll
    for (int j = 0; j < 4; j++)
      acc[i][j] = f32x4{0.f,0.f,0.f,0.f};

  bf16x8 av[4][2], bv[4][2];

  #define RD_A(QM, BASE)                                                   \
    _Pragma("unroll")                                                      \
    for (int _i = 0; _i < 4; _i++)                                         \
      _Pragma("unroll")                                                    \
      for (int _ks = 0; _ks < 2; _ks++)                                    \
        av[_i][_ks] = *(const bf16x8*)((BASE) + roA[(QM)*4+_i] +           \
                       (((_ks*4+g) ^ swA[(QM)*4+_i])<<4));
  #define RD_B(QN, BASE)                                                   \
    _Pragma("unroll")                                                      \
    for (int _j = 0; _j < 2; _j++)                                         \
      _Pragma("unroll")                                                    \
      for (int _ks = 0; _ks < 2; _ks++)                                    \
        bv[(QN)*2+_j][_ks] = *(const bf16x8*)((BASE) + roB[(QN)*2+_j] +    \
                       (((_ks*4+g) ^ swB[(QN)*2+_j])<<4));
  #define MFMAQ(MB, J0)                                                    \
    __builtin_amdgcn_s_setprio(1);                                         \
    _Pragma("unroll")                                                      \
    for (int _ks = 0; _ks < 2; _ks++)                                      \
      _Pragma("unroll")                                                    \
      for (int _m = 0; _m < 4; _m++)                                       \
        _Pragma("unroll")                                                  \
        for (int _j = (J0); _j < (J0)+2; _j++)                             \
          acc[(MB)+_m][_j] = __builtin_amdgcn_mfma_f32_16x16x32_bf16(      \
            bv[_j][_ks], av[_m][_ks], acc[(MB)+_m][_j], 0,0,0);            \
    __builtin_amdgcn_s_setprio(0);

  #define LGKM0() asm volatile("s_waitcnt lgkmcnt(0)" ::: "memory")
  #define LGKM8() asm volatile("s_waitcnt lgkmcnt(8)" ::: "memory")
  #define VM4()   asm volatile("s_waitcnt vmcnt(4)" ::: "memory")
  #define VM0()   asm volatile("s_waitcnt vmcnt(0)" ::: "memory")
  #define BAR()   __builtin_amdgcn_s_barrier()

  const int NT = Kd >> 6;       // 8
  const int NI = NT >> 1;

  SETTILE(0);
  STG(0,0,0); STG(0,0,1); STG(0,0,2); STG(0,0,3);
  STG(1,1,2); STG(1,1,3);
  VM4();
  BAR();

  for (int jt = 0; jt < 4; ++jt){
    for (int i = 0; i < NI; ++i){
      const int kt0 = 2*i, kt1 = kt0 + 1;
      char* bc = smem + (kt0 & 1)*BUFSZ;
      char* bn = smem + (kt1 & 1)*BUFSZ;
      // ph1
      RD_A(0, bc); RD_B(0, bc);
      STG(kt1, kt1 & 1, 0);
      LGKM8();
      BAR();
      LGKM0();
      MFMAQ(0, 0);
      BAR();
      // ph2
      RD_B(1, bc);
      STG(kt1, kt1 & 1, 1);
      BAR();
      LGKM0();
      MFMAQ(0, 2);
      BAR();
      // ph3
      RD_A(1, bc);
      if (kt0+2 < NT) STG(kt0+2, kt0 & 1, 2);
      BAR();
      LGKM0();
      MFMAQ(4, 0);
      BAR();
      // ph4
      if (kt0+2 < NT) STG(kt0+2, kt0 & 1, 3);
      BAR();
      MFMAQ(4, 2);
      VM4();
      BAR();
      // ph5
      RD_A(0, bn); RD_B(0, bn);
      if (kt0+2 < NT) STG(kt0+2, kt0 & 1, 0);
      LGKM8();
      BAR();
      LGKM0();
      MFMAQ(0, 0);
      BAR();
      // ph6
      RD_B(1, bn);
      if (kt0+2 < NT) STG(kt0+2, kt0 & 1, 1);
      BAR();
      LGKM0();
      MFMAQ(0, 2);
      BAR();
      // ph7
      RD_A(1, bn);
      if (kt1+2 < NT) STG(kt1+2, kt1 & 1, 2);
      BAR();
      LGKM0();
      MFMAQ(4, 0);
      BAR();
      // ph8
      if (kt1+2 < NT) STG(kt1+2, kt1 & 1, 3);
      BAR();
      MFMAQ(4, 2);
      if (kt1+2 < NT) VM4(); else VM0();
      BAR();
    }

    // ---- transition: issue NEXT tile's prologue BEFORE epilogue ----
    const int pm0 = m0, pn0 = n0, pby = n0 >> 8;
    if (jt < 3){
      SETTILE(jt + 1);
      STG(0,0,0); STG(0,0,1); STG(0,0,2); STG(0,0,3);
      STG(1,1,2); STG(1,1,3);
    }

    // ---- epilogue for previous tile (raw barriers; no vmcnt drain) ----
    {
      short* outb = outp + bz*sO;
      constexpr float LOG2E = 1.4426950408889634f;
      #pragma unroll
      for (int mi = 0; mi < 8; mi++){
        int lrow = wr*128 + mi*16 + lr;
        int row  = pm0 + lrow;
        float rs = 0.f;
        #pragma unroll
        for (int ni = 0; ni < 4; ni++){
          int col = pn0 + wc*64 + ni*16 + g*4;
          bf16x4 pk;
          #pragma unroll
          for (int i2 = 0; i2 < 4; i2++){
            float p = exp2f(acc[mi][ni][i2]*LOG2E);
            rs += p;
            pk[i2] = f2bf(p);
          }
          *(bf16x4*)&outb[(long long)row*Nn + col] = pk;
        }
        rs += __shfl_xor(rs, 16);
        rs += __shfl_xor(rs, 32);
        if (g == 0) rowpart[lrow*4 + wc] = rs;
      }
      LGKM0();
      BAR();
      if (t < 256){
        float s3 = rowpart[t*4] + rowpart[t*4+1] + rowpart[t*4+2] + rowpart[t*4+3];
        partial[((long long)bz*4096 + pm0 + t)*16 + pby] = s3;
      }
      LGKM0();
      BAR();
    }
    // re-zero acc for next tile
    #pragma unroll
    for (int i = 0; i < 8; i++)
      #pragma unroll
      for (int j = 0; j < 4; j++)
        acc[i][j] = f32x4{0.f,0.f,0.f,0.f};
    if (jt < 3){
      VM4();
      BAR();
    }
  }
  #undef RD_A
  #undef RD_B
  #undef MFMAQ
  #undef LGKM0
  #undef LGKM8
  #undef VM4
  #undef VM0
  #undef BAR
}

// ======= TMxBN bf16 GEMM, TH threads, BK=64, dbuf, counted vmcnt =============
// (r12-verified skeleton; SWZ 3 = A-resident XCD decode, 1-D grid)
template<int MODE, int TM, int BN, int TH, int SWZ>
__global__ __launch_bounds__(TH, 2) void gemmF(
    const short* __restrict__ A, const short* __restrict__ Bw,
    const float* __restrict__ bias,
    void* __restrict__ outp, const float* __restrict__ resid,
    int M, int Nn, int Kd,
    long long sA, long long sB, long long sO, float scale,
    const float* __restrict__ dptr, float* __restrict__ partial)
{
  constexpr int WAVES   = TH/64;
  constexpr int WARPS_N = BN/64;
  constexpr int WARPS_M = WAVES/WARPS_N;
  constexpr int WM = TM/WARPS_M;
  constexpr int MF = WM/16;
  constexpr int ABYT = TM*128;
  constexpr int BUFSZ = (TM+BN)*128;
  constexpr int APASS = (TM*128)/(TH*16);
  constexpr int BPASS = (BN*128)/(TH*16);
  constexpr int LOADS = APASS + BPASS;
  extern __shared__ char smem[];

  int bx, by, bz;
  if constexpr (SWZ == 3){
    // A-resident: each XCD owns 2 bx-strips; (by,bz) inner
    int id = blockIdx.x;
    int xcd = id & 7, s = id >> 3;
    bx = xcd*2 + (s & 1);
    int rem = s >> 1;
    int nby = Nn / BN;
    by = rem % nby; bz = rem / nby;
  } else { bx = blockIdx.x; by = blockIdx.y; bz = blockIdx.z; }

  const short* Ab = A + bz*sA;
  const short* Bb = Bw + bz*sB;
  const int m0 = bx*TM, n0 = by*BN;
  const int t = threadIdx.x;
  const int lane = t & 63, wid = t >> 6;
  const int g = lane >> 4, lr = lane & 15;
  const int wr = wid / WARPS_N, wc = wid % WARPS_N;
  const long long KdLL = Kd;

  auto STAGE = [&](int kt, int buf){
    char* d0 = smem + buf*BUFSZ;
    #pragma unroll
    for (int p = 0; p < APASS; p++){
      int f = p*TH*16 + t*16;
      int row = f >> 7, ch = (f >> 4) & 7;
      gload_lds16(Ab + (long long)(m0+row)*KdLL + (long long)kt*64 + ((ch ^ (row&7))*8),
                  d0 + f);
    }
    #pragma unroll
    for (int p = 0; p < BPASS; p++){
      int f = p*TH*16 + t*16;
      int row = f >> 7, ch = (f >> 4) & 7;
      gload_lds16(Bb + (long long)(n0+row)*KdLL + (long long)kt*64 + ((ch ^ (row&7))*8),
                  d0 + ABYT + f);
    }
  };

  int roA[MF], swA[MF], roB[4], swB[4];
  #pragma unroll
  for (int mf = 0; mf < MF; mf++){
    int ra = wr*WM + mf*16 + lr;
    roA[mf] = ra*128; swA[mf] = ra & 7;
  }
  #pragma unroll
  for (int nf = 0; nf < 4; nf++){
    int rb = wc*64 + nf*16 + lr;
    roB[nf] = ABYT + rb*128; swB[nf] = rb & 7;
  }

  f32x4 acc[MF][4];
  #pragma unroll
  for (int i = 0; i < MF; i++)
    #pragma unroll
    for (int j = 0; j < 4; j++)
      acc[i][j] = f32x4{0.f,0.f,0.f,0.f};

  const int NT = Kd >> 6;

  STAGE(0, 0);
  STAGE(1, 1);
  if constexpr (LOADS == 8) asm volatile("s_waitcnt vmcnt(8)":::"memory");
  else                      asm volatile("s_waitcnt vmcnt(6)":::"memory");
  SB0();
  __builtin_amdgcn_s_barrier();

  for (int kt = 0; kt < NT; ++kt){
    char* base = smem + (kt & 1)*BUFSZ;
    bf16x8 av[MF][2], bv[4][2];
    #pragma unroll
    for (int n = 0; n < 4; n++)
      #pragma unroll
      for (int ks = 0; ks < 2; ks++)
        bv[n][ks] = *(const bf16x8*)(base + roB[n] + (((ks*4+g) ^ swB[n])<<4));
    #pragma unroll
    for (int m = 0; m < MF; m++)
      #pragma unroll
      for (int ks = 0; ks < 2; ks++)
        av[m][ks] = *(const bf16x8*)(base + roA[m] + (((ks*4+g) ^ swA[m])<<4));
    #pragma unroll
    for (int ks = 0; ks < 2; ks++)
      #pragma unroll
      for (int m = 0; m < MF; m++)
        #pragma unroll
        for (int n = 0; n < 4; n++){
          if constexpr (MODE == 2)
            acc[m][n] = __builtin_amdgcn_mfma_f32_16x16x32_bf16(av[m][ks], bv[n][ks], acc[m][n], 0,0,0);
          else
            acc[m][n] = __builtin_amdgcn_mfma_f32_16x16x32_bf16(bv[n][ks], av[m][ks], acc[m][n], 0,0,0);
        }
    SB0();
    __builtin_amdgcn_s_barrier();
    SB0();
    if (kt + 2 < NT){
      STAGE(kt + 2, kt & 1);
      if constexpr (LOADS == 8) asm volatile("s_waitcnt vmcnt(8)":::"memory");
      else                      asm volatile("s_waitcnt vmcnt(6)":::"memory");
    } else {
      asm volatile("s_waitcnt vmcnt(0)":::"memory");
    }
    __builtin_amdgcn_s_barrier();
  }

  if constexpr (MODE == 4){
    short* outb = (short*)outp + bz*sO;
    float* rowpart = (float*)smem;
    constexpr float LOG2E = 1.4426950408889634f;
    #pragma unroll
    for (int mi = 0; mi < MF; mi++){
      int lrow = wr*WM + mi*16 + lr;
      int row  = m0 + lrow;
      float rs = 0.f;
      #pragma unroll
      for (int ni = 0; ni < 4; ni++){
        int col = n0 + wc*64 + ni*16 + g*4;
        bf16x4 pk;
        #pragma unroll
        for (int i = 0; i < 4; i++){
          float p = exp2f(acc[mi][ni][i]*LOG2E);
          rs += p;
          pk[i] = f2bf(p);
        }
        *(bf16x4*)&outb[(long long)row*Nn + col] = pk;
      }
      rs += __shfl_xor(rs, 16);
      rs += __shfl_xor(rs, 32);
      if (g == 0) rowpart[lrow*WARPS_N + wc] = rs;
    }
    __syncthreads();
    if (t < TM){
      float s2 = 0.f;
      #pragma unroll
      for (int j = 0; j < WARPS_N; j++) s2 += rowpart[t*WARPS_N + j];
      partial[((long long)bz*4096 + m0 + t)*16 + by] = s2;
    }
  } else if constexpr (MODE == 5){
    short* outb = (short*)outp + bz*sO;
    const float* dd = dptr + (long long)bz*M;
    #pragma unroll
    for (int mi = 0; mi < MF; mi++){
      int row = m0 + wr*WM + mi*16 + lr;
      float inv = dd[row];
      #pragma unroll
      for (int ni = 0; ni < 4; ni++){
        int col = n0 + wc*64 + ni*16 + g*4;
        bf16x4 pk;
        #pragma unroll
        for (int i = 0; i < 4; i++) pk[i] = f2bf(acc[mi][ni][i]*inv);
        *(bf16x4*)&outb[(long long)row*Nn + col] = pk;
      }
    }
  } else if constexpr (MODE == 6){
    const int seg = by >> 2;
    const long long base = (long long)bz*sO;
    short* qp  = (short*)outp;
    short* kp  = (short*)partial;
    short* vtp = (short*)dptr;
    #pragma unroll
    for (int mi = 0; mi < MF; mi++){
      int row = m0 + wr*WM + mi*16 + lr;
      #pragma unroll
      for (int ni = 0; ni < 4; ni++){
        int col = n0 + wc*64 + ni*16 + g*4;
        float4 bb = *(const float4*)&bias[col];
        int cq = col - seg*512;
        float sc = (seg == 0) ? scale : 1.f;
        bf16x4 pk;
        pk[0] = f2bf((acc[mi][ni][0] + bb.x)*sc);
        pk[1] = f2bf((acc[mi][ni][1] + bb.y)*sc);
        pk[2] = f2bf((acc[mi][ni][2] + bb.z)*sc);
        pk[3] = f2bf((acc[mi][ni][3] + bb.w)*sc);
        if (seg == 0)      *(bf16x4*)&qp[base + (long long)row*512 + cq] = pk;
        else if (seg == 1) *(bf16x4*)&kp[base + (long long)row*512 + cq] = pk;
        else {
          #pragma unroll
          for (int i = 0; i < 4; i++)
            vtp[base + (long long)(cq+i)*4096 + row] = pk[i];
        }
      }
    }
  } else {
    float* outb = (float*)outp + bz*sO;
    const float* rx = resid + bz*sO;
    #pragma unroll
    for (int ni = 0; ni < 4; ni++){
      int col = n0 + wc*64 + ni*16 + lr;
      float bv2 = bias[col];
      #pragma unroll
      for (int mi = 0; mi < MF; mi++){
        int row = m0 + wr*WM + mi*16 + g*4;
        long long off = (long long)col*M + row;
        float4 xr = *(const float4*)&rx[off];
        float4 o;
        o.x = acc[mi][ni][0] + bv2 + xr.x;
        o.y = acc[mi][ni][1] + bv2 + xr.y;
        o.z = acc[mi][ni][2] + bv2 + xr.z;
        o.w = acc[mi][ni][3] + bv2 + xr.w;
        *(float4*)&outb[off] = o;
      }
    }
  }
}

extern "C" void kernel_launch(void* const* d_in, const int* in_sizes, int n_in,
                              void* d_out, int out_size, void* d_ws, size_t ws_size,
                              hipStream_t stream)
{
  const float* x   = (const float*)d_in[0];
  const float* gnw = (const float*)d_in[1];
  const float* gnb = (const float*)d_in[2];
  const float* Wq  = (const float*)d_in[3];
  const float* bq  = (const float*)d_in[4];
  const float* Wk  = (const float*)d_in[5];
  const float* bk  = (const float*)d_in[6];
  const float* Wv  = (const float*)d_in[7];
  const float* bvp = (const float*)d_in[8];
  const float* Wo  = (const float*)d_in[9];
  const float* bo  = (const float*)d_in[10];
  float* out = (float*)d_out;

  char* ws = (char*)d_ws;
  const size_t MB = 1ull << 20;
  short* h      = (short*)(ws);
  short* q      = (short*)(ws + 16*MB);
  short* kmat   = (short*)(ws + 32*MB);
  short* vt     = (short*)(ws + 48*MB);
  short* ao     = (short*)(ws + 64*MB);
  short* wqkv   = (short*)(ws + 80*MB);
  short* wob    = wqkv + 3*262144;
  float* stats  = (float*)(ws + 82*MB);
  float* inv_den= (float*)(ws + 82*MB + 8192);
  float* bqkv   = (float*)(ws + 82*MB + 131072);
  float* partial= (float*)(ws + 83*MB);
  short* S      = (short*)(ws + 84*MB);

  const int LDS_8P = 135168;   // 2x64KB bufs + 4KB rowpart
  const int LDS_SC = 131072;
  const int LDS_QK = 98304;
  const int LDS_BIG = 98304;   // TM=256/BN=128 variants
  hipFuncSetAttribute(reinterpret_cast<const void*>(&gemm8p),
                      hipFuncAttributeMaxDynamicSharedMemorySize, LDS_8P);
  hipFuncSetAttribute(reinterpret_cast<const void*>(&gemmF<4,256,256,512,0>),
                      hipFuncAttributeMaxDynamicSharedMemorySize, LDS_SC);
  hipFuncSetAttribute(reinterpret_cast<const void*>(&gemmF<6,256,128,512,0>),
                      hipFuncAttributeMaxDynamicSharedMemorySize, LDS_QK);
  hipFuncSetAttribute(reinterpret_cast<const void*>(&gemmF<5,256,128,512,3>),
                      hipFuncAttributeMaxDynamicSharedMemorySize, LDS_BIG);
  hipFuncSetAttribute(reinterpret_cast<const void*>(&gemmF<5,256,128,512,0>),
                      hipFuncAttributeMaxDynamicSharedMemorySize, LDS_BIG);
  hipFuncSetAttribute(reinterpret_cast<const void*>(&gemmF<2,256,128,512,0>),
                      hipFuncAttributeMaxDynamicSharedMemorySize, LDS_BIG);

  dim3 blk(256);
  dim3 blk512(512);
  gn_stats<<<dim3(128), blk, 0, stream>>>(x, stats);
  gn_apply<<<dim3(64,4), blk, 0, stream>>>(x, stats, gnw, gnb, h);
  f2bf_all<<<dim3(512), blk, 0, stream>>>(Wq, Wk, Wv, Wo, wqkv, wqkv + 262144, wqkv + 2*262144, wob);
  bcat<<<dim3(2), blk, 0, stream>>>(bq, bk, bvp, bqkv);

  const long long sTok = 4096ll*512;
  const long long sS   = 4096ll*4096;
  const float qscale = 0.044194173824159216f;  // 1/sqrt(512)

  gemmF<6,256,128,512,0><<<dim3(16,12,4), blk512, LDS_QK, stream>>>(
      h, wqkv, bqkv, q, nullptr, 4096, 1536, 512, sTok, 0, sTok, qscale,
      (const float*)vt, (float*)kmat);

  if (ws_size >= 212*MB){
    gemm8p<<<dim3(256), blk512, LDS_8P, stream>>>(
        q, kmat, S, 4096, 512, sTok, sTok, sS, partial);
    reduce_den<<<dim3(64), blk, 0, stream>>>(partial, inv_den, 16384);
    gemmF<5,256,128,512,3><<<dim3(256), blk512, LDS_BIG, stream>>>(
        S, vt, nullptr, ao, nullptr, 4096, 512, 4096, sS, sTok, sTok, 1.f, inv_den, nullptr);
  } else {
    for (int b = 0; b < 4; b++){
      gemmF<4,256,256,512,0><<<dim3(16,16,1), blk512, LDS_SC, stream>>>(
          q + b*sTok, kmat + b*sTok, nullptr, S, nullptr, 4096, 4096, 512, 0, 0, 0, 1.f, nullptr, partial);
      reduce_den<<<dim3(16), blk, 0, stream>>>(partial, inv_den, 4096);
      gemmF<5,256,128,512,0><<<dim3(16,4,1), blk512, LDS_BIG, stream>>>(
          S, vt + b*sTok, nullptr, ao + b*sTok, nullptr, 4096, 512, 4096, 0, 0, 0, 1.f, inv_den, nullptr);
    }
  }

  gemmF<2,256,128,512,0><<<dim3(16,4,4), blk512, LDS_BIG, stream>>>(
      ao, wob, bo, out, x, 4096, 512, 512, sTok, 0, sTok, 1.f, nullptr, nullptr);
}

// Round 15
// 297.014 us; speedup vs baseline: 1.1210x; 1.1210x over previous
//
#include <hip/hip_runtime.h>
#include <hip/hip_bf16.h>

typedef __attribute__((ext_vector_type(8))) short bf16x8;
typedef __attribute__((ext_vector_type(4))) short bf16x4;
typedef __attribute__((ext_vector_type(4))) float f32x4;

__device__ __forceinline__ short f2bf(float f){
  __hip_bfloat16 h = __float2bfloat16(f);
  return __builtin_bit_cast(short, h);
}
__device__ __forceinline__ float bf2f(short s){
  unsigned u = ((unsigned)(unsigned short)s) << 16;
  return __builtin_bit_cast(float, u);
}

__device__ __forceinline__ void gload_lds16(const short* g, char* l){
  __builtin_amdgcn_global_load_lds(
      (const __attribute__((address_space(1))) void*)g,
      (__attribute__((address_space(3))) void*)l, 16, 0, 0);
}

#define SB0() __builtin_amdgcn_sched_barrier(0)

// ---------------- GroupNorm stats ----------------
__global__ __launch_bounds__(256) void gn_stats(const float* __restrict__ x,
                                                float* __restrict__ stats){
  int b = blockIdx.x >> 5, g = blockIdx.x & 31;
  const float4* p = (const float4*)(x + ((long long)b*512 + g*16)*4096);
  float s = 0.f, s2 = 0.f;
  for (int i = threadIdx.x; i < 16384; i += 256){
    float4 v = p[i];
    s  += v.x + v.y + v.z + v.w;
    s2 += v.x*v.x + v.y*v.y + v.z*v.z + v.w*v.w;
  }
  #pragma unroll
  for (int o = 32; o; o >>= 1){ s += __shfl_xor(s, o); s2 += __shfl_xor(s2, o); }
  __shared__ float rs[4], rs2[4];
  int wid = threadIdx.x >> 6;
  if ((threadIdx.x & 63) == 0){ rs[wid] = s; rs2[wid] = s2; }
  __syncthreads();
  if (threadIdx.x == 0){
    float S  = rs[0]+rs[1]+rs[2]+rs[3];
    float S2 = rs2[0]+rs2[1]+rs2[2]+rs2[3];
    float mean = S * (1.f/65536.f);
    float var  = S2 * (1.f/65536.f) - mean*mean;
    stats[blockIdx.x*2]   = mean;
    stats[blockIdx.x*2+1] = rsqrtf(var + 1e-6f);
  }
}

// ------------- GN apply + transpose -> h bf16 [B,N,C] ------------------
__global__ __launch_bounds__(256) void gn_apply(const float* __restrict__ x,
                                                const float* __restrict__ stats,
                                                const float* __restrict__ gw,
                                                const float* __restrict__ gb,
                                                short* __restrict__ h){
  __shared__ float tile[128][65];
  int b  = blockIdx.y;
  int n0 = blockIdx.x * 64;
  int t  = threadIdx.x;
  const float* xb = x + (long long)b*512*4096;
  for (int cc = 0; cc < 4; cc++){
    int c0 = cc*128;
    #pragma unroll
    for (int r = 0; r < 128; r += 4){
      int c = r + (t >> 6);
      tile[c][t & 63] = xb[(long long)(c0+c)*4096 + n0 + (t & 63)];
    }
    __syncthreads();
    int n = t >> 2, cp = (t & 3)*32;
    short tmp[32];
    #pragma unroll
    for (int j = 0; j < 32; j++){
      int c = c0 + cp + j;
      float mean = stats[(b*32 + (c >> 4))*2];
      float rstd = stats[(b*32 + (c >> 4))*2 + 1];
      float v = (tile[cp+j][n] - mean)*rstd*gw[c] + gb[c];
      tmp[j] = f2bf(v);
    }
    long long ho = ((long long)b*4096 + n0 + n)*512 + c0 + cp;
    #pragma unroll
    for (int j2 = 0; j2 < 4; j2++){
      bf16x8 v8;
      #pragma unroll
      for (int e = 0; e < 8; e++) v8[e] = tmp[j2*8 + e];
      *(bf16x8*)&h[ho + j2*8] = v8;
    }
    __syncthreads();
  }
}

// ---------- fp32 -> bf16 weights (wq/wk/wv land contiguously = wqkv) ----------
__global__ __launch_bounds__(256) void f2bf_all(
    const float* __restrict__ w0, const float* __restrict__ w1,
    const float* __restrict__ w2, const float* __restrict__ w3,
    short* __restrict__ o0, short* __restrict__ o1,
    short* __restrict__ o2, short* __restrict__ o3){
  int idx = blockIdx.x*256 + threadIdx.x;
  int m = idx >> 15, r = idx & 32767;
  const float* src = (m==0) ? w0 : (m==1) ? w1 : (m==2) ? w2 : w3;
  short* dst       = (m==0) ? o0 : (m==1) ? o1 : (m==2) ? o2 : o3;
  const float4* p = (const float4*)src + (long long)r*2;
  float4 a = p[0], c = p[1];
  bf16x8 v;
  v[0]=f2bf(a.x); v[1]=f2bf(a.y); v[2]=f2bf(a.z); v[3]=f2bf(a.w);
  v[4]=f2bf(c.x); v[5]=f2bf(c.y); v[6]=f2bf(c.z); v[7]=f2bf(c.w);
  *(bf16x8*)&dst[(long long)r*8] = v;
}

// ---------------- concat q/k/v biases ----------------
__global__ __launch_bounds__(256) void bcat(const float* __restrict__ bq,
                                            const float* __restrict__ bk,
                                            const float* __restrict__ bv,
                                            float* __restrict__ o){
  int t = blockIdx.x*256 + threadIdx.x;
  if (t < 512){ o[t] = bq[t]; o[512+t] = bk[t]; o[1024+t] = bv[t]; }
}

// ---------------- denominator reduce ----------------
__global__ __launch_bounds__(256) void reduce_den(const float* __restrict__ partial,
                                                  float* __restrict__ inv_den,
                                                  int nrows){
  int r = blockIdx.x*256 + threadIdx.x;
  if (r >= nrows) return;
  const float4* p = (const float4*)(partial + (long long)r*16);
  float4 a = p[0], b = p[1], c = p[2], d = p[3];
  float s = a.x+a.y+a.z+a.w + b.x+b.y+b.z+b.w + c.x+c.y+c.z+c.w + d.x+d.y+d.z+d.w;
  inv_den[r] = 1.f / s;
}

// ========== m201-style 8-phase 256x256 scores kernel (MODE4 fused) ===========
// 8 waves (2M x 4N), BK=64, 2 K-tiles/iter, quadrant phases {12,4,8,0} reads,
// lgkm(8) after 12-read phase, lgkm0+setprio+16 MFMA per phase, vmcnt(4) at
// ph4/ph8 ONLY, no sched_barrier in the loop. Stage slots (proven race-free):
// kt1: prev-ph7(B0), prev-ph8(B1), ph1(A0), ph2(A1); kt0+2: ph3(B0), ph4(B1),
// ph5(A0), ph6(A1). Epilogue: p' = exp(acc), bf16 store + partial row sums.
__global__ __launch_bounds__(512, 2) void gemm8(
    const short* __restrict__ A, const short* __restrict__ Bw,
    short* __restrict__ outp,
    int Nn, int Kd,
    long long sA, long long sB, long long sO,
    float* __restrict__ partial)
{
  constexpr int BUFSZ = 65536;            // A 32K | B 32K
  extern __shared__ char smem[];

  // XCD 4x4-region decode (1024 blocks) — verified FETCH-reducing
  int id = blockIdx.x;
  int xcd = id & 7, s = id >> 3;
  int region = xcd + ((s >> 4) << 3);
  int o = s & 15;
  const int bz = region >> 4;
  const int bx = (region & 3)*4 + (o & 3);
  const int by = ((region >> 2) & 3)*4 + (o >> 2);

  const short* Ab = A + bz*sA;
  const short* Bb = Bw + bz*sB;
  const int m0 = bx*256, n0 = by*256;
  const int t = threadIdx.x;
  const int lane = t & 63, wid = t >> 6;
  const int g = lane >> 4, lr = lane & 15;
  const int wr = wid >> 2, wc = wid & 3;
  const long long KdLL = Kd;

  // half-tile stage: 2 gloads, 16KB; which: 0=A0,1=A1,2=B0,3=B1
  auto STG = [&](int kt, int buf, int which){
    const bool isB = which >= 2;
    const int h = which & 1;
    char* d = smem + buf*BUFSZ + (isB ? 32768 : 0) + h*16384 + t*16;
    const short* src = isB ? Bb : Ab;
    const int base = isB ? n0 : m0;
    #pragma unroll
    for (int p = 0; p < 2; p++){
      int row = h*128 + p*64 + (t >> 3);
      int ch = t & 7;
      gload_lds16(src + (long long)(base+row)*KdLL + (long long)kt*64 + ((ch ^ (row&7))*8),
                  d + p*8192);
    }
  };

  int roA[8], swA[8], roB[4], swB[4];
  #pragma unroll
  for (int mf = 0; mf < 8; mf++){
    int ra = wr*128 + mf*16 + lr;
    roA[mf] = ra*128; swA[mf] = ra & 7;
  }
  #pragma unroll
  for (int nf = 0; nf < 4; nf++){
    int rb = wc*64 + nf*16 + lr;
    roB[nf] = 32768 + rb*128; swB[nf] = rb & 7;
  }

  f32x4 acc[8][4];
  #pragma unroll
  for (int i = 0; i < 8; i++)
    #pragma unroll
    for (int j = 0; j < 4; j++)
      acc[i][j] = f32x4{0.f,0.f,0.f,0.f};

  bf16x8 av[4][2], bv[4][2];

  #define RD_A(QM, BASE)                                                   \
    _Pragma("unroll")                                                      \
    for (int _i = 0; _i < 4; _i++)                                         \
      _Pragma("unroll")                                                    \
      for (int _ks = 0; _ks < 2; _ks++)                                    \
        av[_i][_ks] = *(const bf16x8*)((BASE) + roA[(QM)*4+_i] +           \
                       (((_ks*4+g) ^ swA[(QM)*4+_i])<<4));
  #define RD_B(QN, BASE)                                                   \
    _Pragma("unroll")                                                      \
    for (int _j = 0; _j < 2; _j++)                                         \
      _Pragma("unroll")                                                    \
      for (int _ks = 0; _ks < 2; _ks++)                                    \
        bv[(QN)*2+_j][_ks] = *(const bf16x8*)((BASE) + roB[(QN)*2+_j] +    \
                       (((_ks*4+g) ^ swB[(QN)*2+_j])<<4));

  #define LGKM0() asm volatile("s_waitcnt lgkmcnt(0)" ::: "memory")
  #define LGKM8() asm volatile("s_waitcnt lgkmcnt(8)" ::: "memory")
  #define VM4()   asm volatile("s_waitcnt vmcnt(4)" ::: "memory")
  #define VM0()   asm volatile("s_waitcnt vmcnt(0)" ::: "memory")
  #define BAR()   __builtin_amdgcn_s_barrier()

  const int NT = Kd >> 6;       // 8 for K=512
  const int NI = NT >> 1;

  // prologue: A0(0),A1(0),B0(0),B1(0),B0(1),B1(1); tile0 landed, B(1) in flight
  STG(0,0,0); STG(0,0,1); STG(0,0,2); STG(0,0,3);
  STG(1,1,2); STG(1,1,3);
  VM4();
  BAR();

  for (int i = 0; i < NI; ++i){
    const int kt0 = 2*i, kt1 = kt0 + 1;
    char* bc = smem + (kt0 & 1)*BUFSZ;
    char* bn = smem + (kt1 & 1)*BUFSZ;
    {
      // ph1: av qm0 + bv qn0 (12 reads); stage A0(kt1)
      RD_A(0, bc); RD_B(0, bc);
      if (kt1 < NT) STG(kt1, kt1 & 1, 0);
      LGKM8();
      BAR();
      LGKM0();
      __builtin_amdgcn_s_setprio(1);
      #pragma unroll
      for (int _ks = 0; _ks < 2; _ks++)
        #pragma unroll
        for (int _m = 0; _m < 4; _m++)
          #pragma unroll
          for (int _j = 0; _j < 2; _j++)
            acc[_m][_j] = __builtin_amdgcn_mfma_f32_16x16x32_bf16(
              bv[_j][_ks], av[_m][_ks], acc[_m][_j], 0,0,0);
      __builtin_amdgcn_s_setprio(0);
      BAR();
      // ph2: bv qn1 (4 reads); stage A1(kt1)
      RD_B(1, bc);
      if (kt1 < NT) STG(kt1, kt1 & 1, 1);
      BAR();
      LGKM0();
      __builtin_amdgcn_s_setprio(1);
      #pragma unroll
      for (int _ks = 0; _ks < 2; _ks++)
        #pragma unroll
        for (int _m = 0; _m < 4; _m++)
          #pragma unroll
          for (int _j = 2; _j < 4; _j++)
            acc[_m][_j] = __builtin_amdgcn_mfma_f32_16x16x32_bf16(
              bv[_j][_ks], av[_m][_ks], acc[_m][_j], 0,0,0);
      __builtin_amdgcn_s_setprio(0);
      BAR();
      // ph3: av qm1 (8 reads); stage B0(kt0+2)
      RD_A(1, bc);
      if (kt0+2 < NT) STG(kt0+2, kt0 & 1, 2);
      BAR();
      LGKM0();
      __builtin_amdgcn_s_setprio(1);
      #pragma unroll
      for (int _ks = 0; _ks < 2; _ks++)
        #pragma unroll
        for (int _m = 0; _m < 4; _m++)
          #pragma unroll
          for (int _j = 0; _j < 2; _j++)
            acc[4+_m][_j] = __builtin_amdgcn_mfma_f32_16x16x32_bf16(
              bv[_j][_ks], av[_m][_ks], acc[4+_m][_j], 0,0,0);
      __builtin_amdgcn_s_setprio(0);
      BAR();
      // ph4: no reads; stage B1(kt0+2); vmcnt(4)
      if (kt0+2 < NT) STG(kt0+2, kt0 & 1, 3);
      BAR();
      __builtin_amdgcn_s_setprio(1);
      #pragma unroll
      for (int _ks = 0; _ks < 2; _ks++)
        #pragma unroll
        for (int _m = 0; _m < 4; _m++)
          #pragma unroll
          for (int _j = 2; _j < 4; _j++)
            acc[4+_m][_j] = __builtin_amdgcn_mfma_f32_16x16x32_bf16(
              bv[_j][_ks], av[_m][_ks], acc[4+_m][_j], 0,0,0);
      __builtin_amdgcn_s_setprio(0);
      if (kt1 < NT) VM4(); else VM0();
      BAR();
    }
    if (kt1 < NT){
      // ph5: av qm0 + bv qn0; stage A0(kt0+2)
      RD_A(0, bn); RD_B(0, bn);
      if (kt0+2 < NT) STG(kt0+2, kt0 & 1, 0);
      LGKM8();
      BAR();
      LGKM0();
      __builtin_amdgcn_s_setprio(1);
      #pragma unroll
      for (int _ks = 0; _ks < 2; _ks++)
        #pragma unroll
        for (int _m = 0; _m < 4; _m++)
          #pragma unroll
          for (int _j = 0; _j < 2; _j++)
            acc[_m][_j] = __builtin_amdgcn_mfma_f32_16x16x32_bf16(
              bv[_j][_ks], av[_m][_ks], acc[_m][_j], 0,0,0);
      __builtin_amdgcn_s_setprio(0);
      BAR();
      // ph6: bv qn1; stage A1(kt0+2)
      RD_B(1, bn);
      if (kt0+2 < NT) STG(kt0+2, kt0 & 1, 1);
      BAR();
      LGKM0();
      __builtin_amdgcn_s_setprio(1);
      #pragma unroll
      for (int _ks = 0; _ks < 2; _ks++)
        #pragma unroll
        for (int _m = 0; _m < 4; _m++)
          #pragma unroll
          for (int _j = 2; _j < 4; _j++)
            acc[_m][_j] = __builtin_amdgcn_mfma_f32_16x16x32_bf16(
              bv[_j][_ks], av[_m][_ks], acc[_m][_j], 0,0,0);
      __builtin_amdgcn_s_setprio(0);
      BAR();
      // ph7: av qm1; stage B0(kt1+2)
      RD_A(1, bn);
      if (kt1+2 < NT) STG(kt1+2, kt1 & 1, 2);
      BAR();
      LGKM0();
      __builtin_amdgcn_s_setprio(1);
      #pragma unroll
      for (int _ks = 0; _ks < 2; _ks++)
        #pragma unroll
        for (int _m = 0; _m < 4; _m++)
          #pragma unroll
          for (int _j = 0; _j < 2; _j++)
            acc[4+_m][_j] = __builtin_amdgcn_mfma_f32_16x16x32_bf16(
              bv[_j][_ks], av[_m][_ks], acc[4+_m][_j], 0,0,0);
      __builtin_amdgcn_s_setprio(0);
      BAR();
      // ph8: no reads; stage B1(kt1+2); vmcnt(4)
      if (kt1+2 < NT) STG(kt1+2, kt1 & 1, 3);
      BAR();
      __builtin_amdgcn_s_setprio(1);
      #pragma unroll
      for (int _ks = 0; _ks < 2; _ks++)
        #pragma unroll
        for (int _m = 0; _m < 4; _m++)
          #pragma unroll
          for (int _j = 2; _j < 4; _j++)
            acc[4+_m][_j] = __builtin_amdgcn_mfma_f32_16x16x32_bf16(
              bv[_j][_ks], av[_m][_ks], acc[4+_m][_j], 0,0,0);
      __builtin_amdgcn_s_setprio(0);
      if (kt1+2 < NT) VM4(); else VM0();
      BAR();
    }
  }

  // epilogue: p' = exp(acc) bf16 + per-(row,by) partial sums
  short* outb = outp + bz*sO;
  float* rowpart = (float*)smem;
  constexpr float LOG2E = 1.4426950408889634f;
  #pragma unroll
  for (int mi = 0; mi < 8; mi++){
    int lrow = wr*128 + mi*16 + lr;
    int row  = m0 + lrow;
    float rs = 0.f;
    #pragma unroll
    for (int ni = 0; ni < 4; ni++){
      int col = n0 + wc*64 + ni*16 + g*4;
      bf16x4 pk;
      #pragma unroll
      for (int i2 = 0; i2 < 4; i2++){
        float p = exp2f(acc[mi][ni][i2]*LOG2E);
        rs += p;
        pk[i2] = f2bf(p);
      }
      *(bf16x4*)&outb[(long long)row*Nn + col] = pk;
    }
    rs += __shfl_xor(rs, 16);
    rs += __shfl_xor(rs, 32);
    if (g == 0) rowpart[lrow*4 + wc] = rs;
  }
  __syncthreads();
  if (t < 256){
    float s2 = rowpart[t*4] + rowpart[t*4+1] + rowpart[t*4+2] + rowpart[t*4+3];
    partial[((long long)bz*4096 + m0 + t)*16 + by] = s2;
  }
  #undef RD_A
  #undef RD_B
  #undef LGKM0
  #undef LGKM8
  #undef VM4
  #undef VM0
  #undef BAR
}

// ======= TMxBN bf16 GEMM, TH threads, BK=64, dbuf, counted vmcnt =============
// (r12-verified; used for QKV / PV / O-proj and the fallback scores path)
template<int MODE, int TM, int BN, int TH, int SWZ>
__global__ __launch_bounds__(TH, 2) void gemmF(
    const short* __restrict__ A, const short* __restrict__ Bw,
    const float* __restrict__ bias,
    void* __restrict__ outp, const float* __restrict__ resid,
    int M, int Nn, int Kd,
    long long sA, long long sB, long long sO, float scale,
    const float* __restrict__ dptr, float* __restrict__ partial)
{
  constexpr int WAVES   = TH/64;
  constexpr int WARPS_N = BN/64;
  constexpr int WARPS_M = WAVES/WARPS_N;
  constexpr int WM = TM/WARPS_M;
  constexpr int MF = WM/16;
  constexpr int ABYT = TM*128;
  constexpr int BUFSZ = (TM+BN)*128;
  constexpr int APASS = (TM*128)/(TH*16);
  constexpr int BPASS = (BN*128)/(TH*16);
  constexpr int LOADS = APASS + BPASS;
  extern __shared__ char smem[];

  int bx, by, bz;
  if constexpr (SWZ == 2){
    int id = blockIdx.x;
    int xcd = id & 7, s = id >> 3;
    int combo = xcd*2 + (s & 1);
    by = combo & 3; bz = combo >> 2;
    bx = s >> 1;
  } else { bx = blockIdx.x; by = blockIdx.y; bz = blockIdx.z; }

  const short* Ab = A + bz*sA;
  const short* Bb = Bw + bz*sB;
  const int m0 = bx*TM, n0 = by*BN;
  const int t = threadIdx.x;
  const int lane = t & 63, wid = t >> 6;
  const int g = lane >> 4, lr = lane & 15;
  const int wr = wid / WARPS_N, wc = wid % WARPS_N;
  const long long KdLL = Kd;

  auto STAGE = [&](int kt, int buf){
    char* d0 = smem + buf*BUFSZ;
    #pragma unroll
    for (int p = 0; p < APASS; p++){
      int f = p*TH*16 + t*16;
      int row = f >> 7, ch = (f >> 4) & 7;
      gload_lds16(Ab + (long long)(m0+row)*KdLL + (long long)kt*64 + ((ch ^ (row&7))*8),
                  d0 + f);
    }
    #pragma unroll
    for (int p = 0; p < BPASS; p++){
      int f = p*TH*16 + t*16;
      int row = f >> 7, ch = (f >> 4) & 7;
      gload_lds16(Bb + (long long)(n0+row)*KdLL + (long long)kt*64 + ((ch ^ (row&7))*8),
                  d0 + ABYT + f);
    }
  };

  int roA[MF], swA[MF], roB[4], swB[4];
  #pragma unroll
  for (int mf = 0; mf < MF; mf++){
    int ra = wr*WM + mf*16 + lr;
    roA[mf] = ra*128; swA[mf] = ra & 7;
  }
  #pragma unroll
  for (int nf = 0; nf < 4; nf++){
    int rb = wc*64 + nf*16 + lr;
    roB[nf] = ABYT + rb*128; swB[nf] = rb & 7;
  }

  f32x4 acc[MF][4];
  #pragma unroll
  for (int i = 0; i < MF; i++)
    #pragma unroll
    for (int j = 0; j < 4; j++)
      acc[i][j] = f32x4{0.f,0.f,0.f,0.f};

  const int NT = Kd >> 6;

  STAGE(0, 0);
  STAGE(1, 1);
  if constexpr (LOADS == 8) asm volatile("s_waitcnt vmcnt(8)":::"memory");
  else                      asm volatile("s_waitcnt vmcnt(6)":::"memory");
  SB0();
  __builtin_amdgcn_s_barrier();

  for (int kt = 0; kt < NT; ++kt){
    char* base = smem + (kt & 1)*BUFSZ;
    bf16x8 av[MF][2], bv[4][2];
    #pragma unroll
    for (int n = 0; n < 4; n++)
      #pragma unroll
      for (int ks = 0; ks < 2; ks++)
        bv[n][ks] = *(const bf16x8*)(base + roB[n] + (((ks*4+g) ^ swB[n])<<4));
    #pragma unroll
    for (int m = 0; m < MF; m++)
      #pragma unroll
      for (int ks = 0; ks < 2; ks++)
        av[m][ks] = *(const bf16x8*)(base + roA[m] + (((ks*4+g) ^ swA[m])<<4));
    #pragma unroll
    for (int ks = 0; ks < 2; ks++)
      #pragma unroll
      for (int m = 0; m < MF; m++)
        #pragma unroll
        for (int n = 0; n < 4; n++){
          if constexpr (MODE == 2)
            acc[m][n] = __builtin_amdgcn_mfma_f32_16x16x32_bf16(av[m][ks], bv[n][ks], acc[m][n], 0,0,0);
          else
            acc[m][n] = __builtin_amdgcn_mfma_f32_16x16x32_bf16(bv[n][ks], av[m][ks], acc[m][n], 0,0,0);
        }
    SB0();
    __builtin_amdgcn_s_barrier();
    SB0();
    if (kt + 2 < NT){
      STAGE(kt + 2, kt & 1);
      if constexpr (LOADS == 8) asm volatile("s_waitcnt vmcnt(8)":::"memory");
      else                      asm volatile("s_waitcnt vmcnt(6)":::"memory");
    } else {
      asm volatile("s_waitcnt vmcnt(0)":::"memory");
    }
    __builtin_amdgcn_s_barrier();
  }

  if constexpr (MODE == 4){
    short* outb = (short*)outp + bz*sO;
    float* rowpart = (float*)smem;
    constexpr float LOG2E = 1.4426950408889634f;
    #pragma unroll
    for (int mi = 0; mi < MF; mi++){
      int lrow = wr*WM + mi*16 + lr;
      int row  = m0 + lrow;
      float rs = 0.f;
      #pragma unroll
      for (int ni = 0; ni < 4; ni++){
        int col = n0 + wc*64 + ni*16 + g*4;
        bf16x4 pk;
        #pragma unroll
        for (int i = 0; i < 4; i++){
          float p = exp2f(acc[mi][ni][i]*LOG2E);
          rs += p;
          pk[i] = f2bf(p);
        }
        *(bf16x4*)&outb[(long long)row*Nn + col] = pk;
      }
      rs += __shfl_xor(rs, 16);
      rs += __shfl_xor(rs, 32);
      if (g == 0) rowpart[lrow*WARPS_N + wc] = rs;
    }
    __syncthreads();
    if (t < TM){
      float s2 = 0.f;
      #pragma unroll
      for (int j = 0; j < WARPS_N; j++) s2 += rowpart[t*WARPS_N + j];
      partial[((long long)bz*4096 + m0 + t)*16 + by] = s2;
    }
  } else if constexpr (MODE == 5){
    short* outb = (short*)outp + bz*sO;
    const float* dd = dptr + (long long)bz*M;
    #pragma unroll
    for (int mi = 0; mi < MF; mi++){
      int row = m0 + wr*WM + mi*16 + lr;
      float inv = dd[row];
      #pragma unroll
      for (int ni = 0; ni < 4; ni++){
        int col = n0 + wc*64 + ni*16 + g*4;
        bf16x4 pk;
        #pragma unroll
        for (int i = 0; i < 4; i++) pk[i] = f2bf(acc[mi][ni][i]*inv);
        *(bf16x4*)&outb[(long long)row*Nn + col] = pk;
      }
    }
  } else if constexpr (MODE == 6){
    const int seg = by >> 2;
    const long long base = (long long)bz*sO;
    short* qp  = (short*)outp;
    short* kp  = (short*)partial;
    short* vtp = (short*)dptr;
    #pragma unroll
    for (int mi = 0; mi < MF; mi++){
      int row = m0 + wr*WM + mi*16 + lr;
      #pragma unroll
      for (int ni = 0; ni < 4; ni++){
        int col = n0 + wc*64 + ni*16 + g*4;
        float4 bb = *(const float4*)&bias[col];
        int cq = col - seg*512;
        float sc = (seg == 0) ? scale : 1.f;
        bf16x4 pk;
        pk[0] = f2bf((acc[mi][ni][0] + bb.x)*sc);
        pk[1] = f2bf((acc[mi][ni][1] + bb.y)*sc);
        pk[2] = f2bf((acc[mi][ni][2] + bb.z)*sc);
        pk[3] = f2bf((acc[mi][ni][3] + bb.w)*sc);
        if (seg == 0)      *(bf16x4*)&qp[base + (long long)row*512 + cq] = pk;
        else if (seg == 1) *(bf16x4*)&kp[base + (long long)row*512 + cq] = pk;
        else {
          #pragma unroll
          for (int i = 0; i < 4; i++)
            vtp[base + (long long)(cq+i)*4096 + row] = pk[i];
        }
      }
    }
  } else {
    float* outb = (float*)outp + bz*sO;
    const float* rx = resid + bz*sO;
    #pragma unroll
    for (int ni = 0; ni < 4; ni++){
      int col = n0 + wc*64 + ni*16 + lr;
      float bv2 = bias[col];
      #pragma unroll
      for (int mi = 0; mi < MF; mi++){
        int row = m0 + wr*WM + mi*16 + g*4;
        long long off = (long long)col*M + row;
        float4 xr = *(const float4*)&rx[off];
        float4 o;
        o.x = acc[mi][ni][0] + bv2 + xr.x;
        o.y = acc[mi][ni][1] + bv2 + xr.y;
        o.z = acc[mi][ni][2] + bv2 + xr.z;
        o.w = acc[mi][ni][3] + bv2 + xr.w;
        *(float4*)&outb[off] = o;
      }
    }
  }
}

extern "C" void kernel_launch(void* const* d_in, const int* in_sizes, int n_in,
                              void* d_out, int out_size, void* d_ws, size_t ws_size,
                              hipStream_t stream)
{
  const float* x   = (const float*)d_in[0];
  const float* gnw = (const float*)d_in[1];
  const float* gnb = (const float*)d_in[2];
  const float* Wq  = (const float*)d_in[3];
  const float* bq  = (const float*)d_in[4];
  const float* Wk  = (const float*)d_in[5];
  const float* bk  = (const float*)d_in[6];
  const float* Wv  = (const float*)d_in[7];
  const float* bvp = (const float*)d_in[8];
  const float* Wo  = (const float*)d_in[9];
  const float* bo  = (const float*)d_in[10];
  float* out = (float*)d_out;

  char* ws = (char*)d_ws;
  const size_t MB = 1ull << 20;
  short* h      = (short*)(ws);
  short* q      = (short*)(ws + 16*MB);
  short* kmat   = (short*)(ws + 32*MB);
  short* vt     = (short*)(ws + 48*MB);
  short* ao     = (short*)(ws + 64*MB);
  short* wqkv   = (short*)(ws + 80*MB);
  short* wob    = wqkv + 3*262144;
  float* stats  = (float*)(ws + 82*MB);
  float* inv_den= (float*)(ws + 82*MB + 8192);
  float* bqkv   = (float*)(ws + 82*MB + 131072);
  float* partial= (float*)(ws + 83*MB);
  short* S      = (short*)(ws + 84*MB);

  const int LDS_8P = 131072;
  const int LDS_SC = 131072;
  const int LDS_QK = 98304;
  const int LDS_PV = 65536;
  hipFuncSetAttribute(reinterpret_cast<const void*>(&gemm8),
                      hipFuncAttributeMaxDynamicSharedMemorySize, LDS_8P);
  hipFuncSetAttribute(reinterpret_cast<const void*>(&gemmF<4,256,256,512,0>),
                      hipFuncAttributeMaxDynamicSharedMemorySize, LDS_SC);
  hipFuncSetAttribute(reinterpret_cast<const void*>(&gemmF<6,256,128,512,0>),
                      hipFuncAttributeMaxDynamicSharedMemorySize, LDS_QK);
  hipFuncSetAttribute(reinterpret_cast<const void*>(&gemmF<5,128,128,256,2>),
                      hipFuncAttributeMaxDynamicSharedMemorySize, LDS_PV);
  hipFuncSetAttribute(reinterpret_cast<const void*>(&gemmF<5,128,128,256,0>),
                      hipFuncAttributeMaxDynamicSharedMemorySize, LDS_PV);
  hipFuncSetAttribute(reinterpret_cast<const void*>(&gemmF<2,128,128,256,0>),
                      hipFuncAttributeMaxDynamicSharedMemorySize, LDS_PV);

  dim3 blk(256);
  dim3 blk512(512);
  gn_stats<<<dim3(128), blk, 0, stream>>>(x, stats);
  gn_apply<<<dim3(64,4), blk, 0, stream>>>(x, stats, gnw, gnb, h);
  f2bf_all<<<dim3(512), blk, 0, stream>>>(Wq, Wk, Wv, Wo, wqkv, wqkv + 262144, wqkv + 2*262144, wob);
  bcat<<<dim3(2), blk, 0, stream>>>(bq, bk, bvp, bqkv);

  const long long sTok = 4096ll*512;
  const long long sS   = 4096ll*4096;
  const float qscale = 0.044194173824159216f;  // 1/sqrt(512)

  gemmF<6,256,128,512,0><<<dim3(16,12,4), blk512, LDS_QK, stream>>>(
      h, wqkv, bqkv, q, nullptr, 4096, 1536, 512, sTok, 0, sTok, qscale,
      (const float*)vt, (float*)kmat);

  if (ws_size >= 212*MB){
    gemm8<<<dim3(1024), blk512, LDS_8P, stream>>>(
        q, kmat, S, 4096, 512, sTok, sTok, sS, partial);
    reduce_den<<<dim3(64), blk, 0, stream>>>(partial, inv_den, 16384);
    gemmF<5,128,128,256,2><<<dim3(512), blk, LDS_PV, stream>>>(
        S, vt, nullptr, ao, nullptr, 4096, 512, 4096, sS, sTok, sTok, 1.f, inv_den, nullptr);
  } else {
    for (int b = 0; b < 4; b++){
      gemmF<4,256,256,512,0><<<dim3(16,16,1), blk512, LDS_SC, stream>>>(
          q + b*sTok, kmat + b*sTok, nullptr, S, nullptr, 4096, 4096, 512, 0, 0, 0, 1.f, nullptr, partial);
      reduce_den<<<dim3(16), blk, 0, stream>>>(partial, inv_den, 4096);
      gemmF<5,128,128,256,0><<<dim3(32,4,1), blk, LDS_PV, stream>>>(
          S, vt + b*sTok, nullptr, ao + b*sTok, nullptr, 4096, 512, 4096, 0, 0, 0, 1.f, inv_den, nullptr);
    }
  }

  gemmF<2,128,128,256,0><<<dim3(32,4,4), blk, LDS_PV, stream>>>(
      ao, wob, bo, out, x, 4096, 512, 512, sTok, 0, sTok, 1.f, nullptr, nullptr);
}

// Round 16
// 293.779 us; speedup vs baseline: 1.1333x; 1.0110x over previous
//
#include <hip/hip_runtime.h>
#include <hip/hip_bf16.h>

typedef __attribute__((ext_vector_type(8))) short bf16x8;
typedef __attribute__((ext_vector_type(4))) short bf16x4;
typedef __attribute__((ext_vector_type(4))) float f32x4;

__device__ __forceinline__ short f2bf(float f){
  __hip_bfloat16 h = __float2bfloat16(f);
  return __builtin_bit_cast(short, h);
}
__device__ __forceinline__ float bf2f(short s){
  unsigned u = ((unsigned)(unsigned short)s) << 16;
  return __builtin_bit_cast(float, u);
}

__device__ __forceinline__ void gload_lds16(const short* g, char* l){
  __builtin_amdgcn_global_load_lds(
      (const __attribute__((address_space(1))) void*)g,
      (__attribute__((address_space(3))) void*)l, 16, 0, 0);
}

#define SB0() __builtin_amdgcn_sched_barrier(0)

// ---------------- GroupNorm stats ----------------
__global__ __launch_bounds__(256) void gn_stats(const float* __restrict__ x,
                                                float* __restrict__ stats){
  int b = blockIdx.x >> 5, g = blockIdx.x & 31;
  const float4* p = (const float4*)(x + ((long long)b*512 + g*16)*4096);
  float s = 0.f, s2 = 0.f;
  for (int i = threadIdx.x; i < 16384; i += 256){
    float4 v = p[i];
    s  += v.x + v.y + v.z + v.w;
    s2 += v.x*v.x + v.y*v.y + v.z*v.z + v.w*v.w;
  }
  #pragma unroll
  for (int o = 32; o; o >>= 1){ s += __shfl_xor(s, o); s2 += __shfl_xor(s2, o); }
  __shared__ float rs[4], rs2[4];
  int wid = threadIdx.x >> 6;
  if ((threadIdx.x & 63) == 0){ rs[wid] = s; rs2[wid] = s2; }
  __syncthreads();
  if (threadIdx.x == 0){
    float S  = rs[0]+rs[1]+rs[2]+rs[3];
    float S2 = rs2[0]+rs2[1]+rs2[2]+rs2[3];
    float mean = S * (1.f/65536.f);
    float var  = S2 * (1.f/65536.f) - mean*mean;
    stats[blockIdx.x*2]   = mean;
    stats[blockIdx.x*2+1] = rsqrtf(var + 1e-6f);
  }
}

// ------------- GN apply + transpose -> h bf16 [B,N,C] ------------------
__global__ __launch_bounds__(256) void gn_apply(const float* __restrict__ x,
                                                const float* __restrict__ stats,
                                                const float* __restrict__ gw,
                                                const float* __restrict__ gb,
                                                short* __restrict__ h){
  __shared__ float tile[128][65];
  int b  = blockIdx.y;
  int n0 = blockIdx.x * 64;
  int t  = threadIdx.x;
  const float* xb = x + (long long)b*512*4096;
  for (int cc = 0; cc < 4; cc++){
    int c0 = cc*128;
    #pragma unroll
    for (int r = 0; r < 128; r += 4){
      int c = r + (t >> 6);
      tile[c][t & 63] = xb[(long long)(c0+c)*4096 + n0 + (t & 63)];
    }
    __syncthreads();
    int n = t >> 2, cp = (t & 3)*32;
    short tmp[32];
    #pragma unroll
    for (int j = 0; j < 32; j++){
      int c = c0 + cp + j;
      float mean = stats[(b*32 + (c >> 4))*2];
      float rstd = stats[(b*32 + (c >> 4))*2 + 1];
      float v = (tile[cp+j][n] - mean)*rstd*gw[c] + gb[c];
      tmp[j] = f2bf(v);
    }
    long long ho = ((long long)b*4096 + n0 + n)*512 + c0 + cp;
    #pragma unroll
    for (int j2 = 0; j2 < 4; j2++){
      bf16x8 v8;
      #pragma unroll
      for (int e = 0; e < 8; e++) v8[e] = tmp[j2*8 + e];
      *(bf16x8*)&h[ho + j2*8] = v8;
    }
    __syncthreads();
  }
}

// ---- fp32 -> bf16 weights (wq/wk/wv contiguous) + fused q/k/v bias concat ----
__global__ __launch_bounds__(256) void f2bf_all(
    const float* __restrict__ w0, const float* __restrict__ w1,
    const float* __restrict__ w2, const float* __restrict__ w3,
    short* __restrict__ o0, short* __restrict__ o1,
    short* __restrict__ o2, short* __restrict__ o3,
    const float* __restrict__ bq, const float* __restrict__ bk,
    const float* __restrict__ bv, float* __restrict__ bqkv){
  int idx = blockIdx.x*256 + threadIdx.x;
  int m = idx >> 15, r = idx & 32767;
  const float* src = (m==0) ? w0 : (m==1) ? w1 : (m==2) ? w2 : w3;
  short* dst       = (m==0) ? o0 : (m==1) ? o1 : (m==2) ? o2 : o3;
  const float4* p = (const float4*)src + (long long)r*2;
  float4 a = p[0], c = p[1];
  bf16x8 v;
  v[0]=f2bf(a.x); v[1]=f2bf(a.y); v[2]=f2bf(a.z); v[3]=f2bf(a.w);
  v[4]=f2bf(c.x); v[5]=f2bf(c.y); v[6]=f2bf(c.z); v[7]=f2bf(c.w);
  *(bf16x8*)&dst[(long long)r*8] = v;
  if (idx < 512){
    bqkv[idx]      = bq[idx];
    bqkv[512+idx]  = bk[idx];
    bqkv[1024+idx] = bv[idx];
  }
}

// ========== m201-style 8-phase 256x256 scores kernel (MODE4 fused) ===========
// 8 waves (2M x 4N), BK=64, 2 K-tiles/iter, quadrant phases {12,4,8,0} reads,
// lgkm(8) after 12-read phase, lgkm0+setprio+16 MFMA per phase, vmcnt(4) at
// ph4/ph8 ONLY, no sched_barrier in the loop. Stage slots (proven race-free):
// kt1: prev-ph7(B0), prev-ph8(B1), ph1(A0), ph2(A1); kt0+2: ph3(B0), ph4(B1),
// ph5(A0), ph6(A1). Epilogue: p' = exp(acc), bf16 store + partial row sums.
__global__ __launch_bounds__(512, 2) void gemm8(
    const short* __restrict__ A, const short* __restrict__ Bw,
    short* __restrict__ outp,
    int Nn, int Kd,
    long long sA, long long sB, long long sO,
    float* __restrict__ partial)
{
  constexpr int BUFSZ = 65536;            // A 32K | B 32K
  extern __shared__ char smem[];

  // XCD 4x4-region decode (1024 blocks) — verified FETCH-reducing
  int id = blockIdx.x;
  int xcd = id & 7, s = id >> 3;
  int region = xcd + ((s >> 4) << 3);
  int o = s & 15;
  const int bz = region >> 4;
  const int bx = (region & 3)*4 + (o & 3);
  const int by = ((region >> 2) & 3)*4 + (o >> 2);

  const short* Ab = A + bz*sA;
  const short* Bb = Bw + bz*sB;
  const int m0 = bx*256, n0 = by*256;
  const int t = threadIdx.x;
  const int lane = t & 63, wid = t >> 6;
  const int g = lane >> 4, lr = lane & 15;
  const int wr = wid >> 2, wc = wid & 3;
  const long long KdLL = Kd;

  // half-tile stage: 2 gloads, 16KB; which: 0=A0,1=A1,2=B0,3=B1
  auto STG = [&](int kt, int buf, int which){
    const bool isB = which >= 2;
    const int h = which & 1;
    char* d = smem + buf*BUFSZ + (isB ? 32768 : 0) + h*16384 + t*16;
    const short* src = isB ? Bb : Ab;
    const int base = isB ? n0 : m0;
    #pragma unroll
    for (int p = 0; p < 2; p++){
      int row = h*128 + p*64 + (t >> 3);
      int ch = t & 7;
      gload_lds16(src + (long long)(base+row)*KdLL + (long long)kt*64 + ((ch ^ (row&7))*8),
                  d + p*8192);
    }
  };

  int roA[8], swA[8], roB[4], swB[4];
  #pragma unroll
  for (int mf = 0; mf < 8; mf++){
    int ra = wr*128 + mf*16 + lr;
    roA[mf] = ra*128; swA[mf] = ra & 7;
  }
  #pragma unroll
  for (int nf = 0; nf < 4; nf++){
    int rb = wc*64 + nf*16 + lr;
    roB[nf] = 32768 + rb*128; swB[nf] = rb & 7;
  }

  f32x4 acc[8][4];
  #pragma unroll
  for (int i = 0; i < 8; i++)
    #pragma unroll
    for (int j = 0; j < 4; j++)
      acc[i][j] = f32x4{0.f,0.f,0.f,0.f};

  bf16x8 av[4][2], bv[4][2];

  #define RD_A(QM, BASE)                                                   \
    _Pragma("unroll")                                                      \
    for (int _i = 0; _i < 4; _i++)                                         \
      _Pragma("unroll")                                                    \
      for (int _ks = 0; _ks < 2; _ks++)                                    \
        av[_i][_ks] = *(const bf16x8*)((BASE) + roA[(QM)*4+_i] +           \
                       (((_ks*4+g) ^ swA[(QM)*4+_i])<<4));
  #define RD_B(QN, BASE)                                                   \
    _Pragma("unroll")                                                      \
    for (int _j = 0; _j < 2; _j++)                                         \
      _Pragma("unroll")                                                    \
      for (int _ks = 0; _ks < 2; _ks++)                                    \
        bv[(QN)*2+_j][_ks] = *(const bf16x8*)((BASE) + roB[(QN)*2+_j] +    \
                       (((_ks*4+g) ^ swB[(QN)*2+_j])<<4));

  #define LGKM0() asm volatile("s_waitcnt lgkmcnt(0)" ::: "memory")
  #define LGKM8() asm volatile("s_waitcnt lgkmcnt(8)" ::: "memory")
  #define VM4()   asm volatile("s_waitcnt vmcnt(4)" ::: "memory")
  #define VM0()   asm volatile("s_waitcnt vmcnt(0)" ::: "memory")
  #define BAR()   __builtin_amdgcn_s_barrier()

  const int NT = Kd >> 6;       // 8 for K=512
  const int NI = NT >> 1;

  // prologue: A0(0),A1(0),B0(0),B1(0),B0(1),B1(1); tile0 landed, B(1) in flight
  STG(0,0,0); STG(0,0,1); STG(0,0,2); STG(0,0,3);
  STG(1,1,2); STG(1,1,3);
  VM4();
  BAR();

  for (int i = 0; i < NI; ++i){
    const int kt0 = 2*i, kt1 = kt0 + 1;
    char* bc = smem + (kt0 & 1)*BUFSZ;
    char* bn = smem + (kt1 & 1)*BUFSZ;
    {
      // ph1: av qm0 + bv qn0 (12 reads); stage A0(kt1)
      RD_A(0, bc); RD_B(0, bc);
      if (kt1 < NT) STG(kt1, kt1 & 1, 0);
      LGKM8();
      BAR();
      LGKM0();
      __builtin_amdgcn_s_setprio(1);
      #pragma unroll
      for (int _ks = 0; _ks < 2; _ks++)
        #pragma unroll
        for (int _m = 0; _m < 4; _m++)
          #pragma unroll
          for (int _j = 0; _j < 2; _j++)
            acc[_m][_j] = __builtin_amdgcn_mfma_f32_16x16x32_bf16(
              bv[_j][_ks], av[_m][_ks], acc[_m][_j], 0,0,0);
      __builtin_amdgcn_s_setprio(0);
      BAR();
      // ph2: bv qn1 (4 reads); stage A1(kt1)
      RD_B(1, bc);
      if (kt1 < NT) STG(kt1, kt1 & 1, 1);
      BAR();
      LGKM0();
      __builtin_amdgcn_s_setprio(1);
      #pragma unroll
      for (int _ks = 0; _ks < 2; _ks++)
        #pragma unroll
        for (int _m = 0; _m < 4; _m++)
          #pragma unroll
          for (int _j = 2; _j < 4; _j++)
            acc[_m][_j] = __builtin_amdgcn_mfma_f32_16x16x32_bf16(
              bv[_j][_ks], av[_m][_ks], acc[_m][_j], 0,0,0);
      __builtin_amdgcn_s_setprio(0);
      BAR();
      // ph3: av qm1 (8 reads); stage B0(kt0+2)
      RD_A(1, bc);
      if (kt0+2 < NT) STG(kt0+2, kt0 & 1, 2);
      BAR();
      LGKM0();
      __builtin_amdgcn_s_setprio(1);
      #pragma unroll
      for (int _ks = 0; _ks < 2; _ks++)
        #pragma unroll
        for (int _m = 0; _m < 4; _m++)
          #pragma unroll
          for (int _j = 0; _j < 2; _j++)
            acc[4+_m][_j] = __builtin_amdgcn_mfma_f32_16x16x32_bf16(
              bv[_j][_ks], av[_m][_ks], acc[4+_m][_j], 0,0,0);
      __builtin_amdgcn_s_setprio(0);
      BAR();
      // ph4: no reads; stage B1(kt0+2); vmcnt(4)
      if (kt0+2 < NT) STG(kt0+2, kt0 & 1, 3);
      BAR();
      __builtin_amdgcn_s_setprio(1);
      #pragma unroll
      for (int _ks = 0; _ks < 2; _ks++)
        #pragma unroll
        for (int _m = 0; _m < 4; _m++)
          #pragma unroll
          for (int _j = 2; _j < 4; _j++)
            acc[4+_m][_j] = __builtin_amdgcn_mfma_f32_16x16x32_bf16(
              bv[_j][_ks], av[_m][_ks], acc[4+_m][_j], 0,0,0);
      __builtin_amdgcn_s_setprio(0);
      if (kt1 < NT) VM4(); else VM0();
      BAR();
    }
    if (kt1 < NT){
      // ph5: av qm0 + bv qn0; stage A0(kt0+2)
      RD_A(0, bn); RD_B(0, bn);
      if (kt0+2 < NT) STG(kt0+2, kt0 & 1, 0);
      LGKM8();
      BAR();
      LGKM0();
      __builtin_amdgcn_s_setprio(1);
      #pragma unroll
      for (int _ks = 0; _ks < 2; _ks++)
        #pragma unroll
        for (int _m = 0; _m < 4; _m++)
          #pragma unroll
          for (int _j = 0; _j < 2; _j++)
            acc[_m][_j] = __builtin_amdgcn_mfma_f32_16x16x32_bf16(
              bv[_j][_ks], av[_m][_ks], acc[_m][_j], 0,0,0);
      __builtin_amdgcn_s_setprio(0);
      BAR();
      // ph6: bv qn1; stage A1(kt0+2)
      RD_B(1, bn);
      if (kt0+2 < NT) STG(kt0+2, kt0 & 1, 1);
      BAR();
      LGKM0();
      __builtin_amdgcn_s_setprio(1);
      #pragma unroll
      for (int _ks = 0; _ks < 2; _ks++)
        #pragma unroll
        for (int _m = 0; _m < 4; _m++)
          #pragma unroll
          for (int _j = 2; _j < 4; _j++)
            acc[_m][_j] = __builtin_amdgcn_mfma_f32_16x16x32_bf16(
              bv[_j][_ks], av[_m][_ks], acc[_m][_j], 0,0,0);
      __builtin_amdgcn_s_setprio(0);
      BAR();
      // ph7: av qm1; stage B0(kt1+2)
      RD_A(1, bn);
      if (kt1+2 < NT) STG(kt1+2, kt1 & 1, 2);
      BAR();
      LGKM0();
      __builtin_amdgcn_s_setprio(1);
      #pragma unroll
      for (int _ks = 0; _ks < 2; _ks++)
        #pragma unroll
        for (int _m = 0; _m < 4; _m++)
          #pragma unroll
          for (int _j = 0; _j < 2; _j++)
            acc[4+_m][_j] = __builtin_amdgcn_mfma_f32_16x16x32_bf16(
              bv[_j][_ks], av[_m][_ks], acc[4+_m][_j], 0,0,0);
      __builtin_amdgcn_s_setprio(0);
      BAR();
      // ph8: no reads; stage B1(kt1+2); vmcnt(4)
      if (kt1+2 < NT) STG(kt1+2, kt1 & 1, 3);
      BAR();
      __builtin_amdgcn_s_setprio(1);
      #pragma unroll
      for (int _ks = 0; _ks < 2; _ks++)
        #pragma unroll
        for (int _m = 0; _m < 4; _m++)
          #pragma unroll
          for (int _j = 2; _j < 4; _j++)
            acc[4+_m][_j] = __builtin_amdgcn_mfma_f32_16x16x32_bf16(
              bv[_j][_ks], av[_m][_ks], acc[4+_m][_j], 0,0,0);
      __builtin_amdgcn_s_setprio(0);
      if (kt1+2 < NT) VM4(); else VM0();
      BAR();
    }
  }

  // epilogue: p' = exp(acc) bf16 + per-(row,by) partial sums
  short* outb = outp + bz*sO;
  float* rowpart = (float*)smem;
  constexpr float LOG2E = 1.4426950408889634f;
  #pragma unroll
  for (int mi = 0; mi < 8; mi++){
    int lrow = wr*128 + mi*16 + lr;
    int row  = m0 + lrow;
    float rs = 0.f;
    #pragma unroll
    for (int ni = 0; ni < 4; ni++){
      int col = n0 + wc*64 + ni*16 + g*4;
      bf16x4 pk;
      #pragma unroll
      for (int i2 = 0; i2 < 4; i2++){
        float p = exp2f(acc[mi][ni][i2]*LOG2E);
        rs += p;
        pk[i2] = f2bf(p);
      }
      *(bf16x4*)&outb[(long long)row*Nn + col] = pk;
    }
    rs += __shfl_xor(rs, 16);
    rs += __shfl_xor(rs, 32);
    if (g == 0) rowpart[lrow*4 + wc] = rs;
  }
  __syncthreads();
  if (t < 256){
    float s2 = rowpart[t*4] + rowpart[t*4+1] + rowpart[t*4+2] + rowpart[t*4+3];
    partial[((long long)bz*4096 + m0 + t)*16 + by] = s2;
  }
  #undef RD_A
  #undef RD_B
  #undef LGKM0
  #undef LGKM8
  #undef VM4
  #undef VM0
  #undef BAR
}

// ======= TMxBN bf16 GEMM, TH threads, BK=64, dbuf, counted vmcnt =============
// (r12-verified; QKV / PV / O-proj + fallback scores)
// MODE 5 (PV) now fuses the denominator reduction: dptr = partial[.][16],
// each lane sums its row's 16 partials inline (L2-hot) -> no reduce_den kernel.
template<int MODE, int TM, int BN, int TH, int SWZ>
__global__ __launch_bounds__(TH, 2) void gemmF(
    const short* __restrict__ A, const short* __restrict__ Bw,
    const float* __restrict__ bias,
    void* __restrict__ outp, const float* __restrict__ resid,
    int M, int Nn, int Kd,
    long long sA, long long sB, long long sO, float scale,
    const float* __restrict__ dptr, float* __restrict__ partial)
{
  constexpr int WAVES   = TH/64;
  constexpr int WARPS_N = BN/64;
  constexpr int WARPS_M = WAVES/WARPS_N;
  constexpr int WM = TM/WARPS_M;
  constexpr int MF = WM/16;
  constexpr int ABYT = TM*128;
  constexpr int BUFSZ = (TM+BN)*128;
  constexpr int APASS = (TM*128)/(TH*16);
  constexpr int BPASS = (BN*128)/(TH*16);
  constexpr int LOADS = APASS + BPASS;
  extern __shared__ char smem[];

  int bx, by, bz;
  if constexpr (SWZ == 2){
    int id = blockIdx.x;
    int xcd = id & 7, s = id >> 3;
    int combo = xcd*2 + (s & 1);
    by = combo & 3; bz = combo >> 2;
    bx = s >> 1;
  } else { bx = blockIdx.x; by = blockIdx.y; bz = blockIdx.z; }

  const short* Ab = A + bz*sA;
  const short* Bb = Bw + bz*sB;
  const int m0 = bx*TM, n0 = by*BN;
  const int t = threadIdx.x;
  const int lane = t & 63, wid = t >> 6;
  const int g = lane >> 4, lr = lane & 15;
  const int wr = wid / WARPS_N, wc = wid % WARPS_N;
  const long long KdLL = Kd;

  auto STAGE = [&](int kt, int buf){
    char* d0 = smem + buf*BUFSZ;
    #pragma unroll
    for (int p = 0; p < APASS; p++){
      int f = p*TH*16 + t*16;
      int row = f >> 7, ch = (f >> 4) & 7;
      gload_lds16(Ab + (long long)(m0+row)*KdLL + (long long)kt*64 + ((ch ^ (row&7))*8),
                  d0 + f);
    }
    #pragma unroll
    for (int p = 0; p < BPASS; p++){
      int f = p*TH*16 + t*16;
      int row = f >> 7, ch = (f >> 4) & 7;
      gload_lds16(Bb + (long long)(n0+row)*KdLL + (long long)kt*64 + ((ch ^ (row&7))*8),
                  d0 + ABYT + f);
    }
  };

  int roA[MF], swA[MF], roB[4], swB[4];
  #pragma unroll
  for (int mf = 0; mf < MF; mf++){
    int ra = wr*WM + mf*16 + lr;
    roA[mf] = ra*128; swA[mf] = ra & 7;
  }
  #pragma unroll
  for (int nf = 0; nf < 4; nf++){
    int rb = wc*64 + nf*16 + lr;
    roB[nf] = ABYT + rb*128; swB[nf] = rb & 7;
  }

  f32x4 acc[MF][4];
  #pragma unroll
  for (int i = 0; i < MF; i++)
    #pragma unroll
    for (int j = 0; j < 4; j++)
      acc[i][j] = f32x4{0.f,0.f,0.f,0.f};

  const int NT = Kd >> 6;

  STAGE(0, 0);
  STAGE(1, 1);
  if constexpr (LOADS == 8) asm volatile("s_waitcnt vmcnt(8)":::"memory");
  else                      asm volatile("s_waitcnt vmcnt(6)":::"memory");
  SB0();
  __builtin_amdgcn_s_barrier();

  for (int kt = 0; kt < NT; ++kt){
    char* base = smem + (kt & 1)*BUFSZ;
    bf16x8 av[MF][2], bv[4][2];
    #pragma unroll
    for (int n = 0; n < 4; n++)
      #pragma unroll
      for (int ks = 0; ks < 2; ks++)
        bv[n][ks] = *(const bf16x8*)(base + roB[n] + (((ks*4+g) ^ swB[n])<<4));
    #pragma unroll
    for (int m = 0; m < MF; m++)
      #pragma unroll
      for (int ks = 0; ks < 2; ks++)
        av[m][ks] = *(const bf16x8*)(base + roA[m] + (((ks*4+g) ^ swA[m])<<4));
    #pragma unroll
    for (int ks = 0; ks < 2; ks++)
      #pragma unroll
      for (int m = 0; m < MF; m++)
        #pragma unroll
        for (int n = 0; n < 4; n++){
          if constexpr (MODE == 2)
            acc[m][n] = __builtin_amdgcn_mfma_f32_16x16x32_bf16(av[m][ks], bv[n][ks], acc[m][n], 0,0,0);
          else
            acc[m][n] = __builtin_amdgcn_mfma_f32_16x16x32_bf16(bv[n][ks], av[m][ks], acc[m][n], 0,0,0);
        }
    SB0();
    __builtin_amdgcn_s_barrier();
    SB0();
    if (kt + 2 < NT){
      STAGE(kt + 2, kt & 1);
      if constexpr (LOADS == 8) asm volatile("s_waitcnt vmcnt(8)":::"memory");
      else                      asm volatile("s_waitcnt vmcnt(6)":::"memory");
    } else {
      asm volatile("s_waitcnt vmcnt(0)":::"memory");
    }
    __builtin_amdgcn_s_barrier();
  }

  if constexpr (MODE == 4){
    short* outb = (short*)outp + bz*sO;
    float* rowpart = (float*)smem;
    constexpr float LOG2E = 1.4426950408889634f;
    #pragma unroll
    for (int mi = 0; mi < MF; mi++){
      int lrow = wr*WM + mi*16 + lr;
      int row  = m0 + lrow;
      float rs = 0.f;
      #pragma unroll
      for (int ni = 0; ni < 4; ni++){
        int col = n0 + wc*64 + ni*16 + g*4;
        bf16x4 pk;
        #pragma unroll
        for (int i = 0; i < 4; i++){
          float p = exp2f(acc[mi][ni][i]*LOG2E);
          rs += p;
          pk[i] = f2bf(p);
        }
        *(bf16x4*)&outb[(long long)row*Nn + col] = pk;
      }
      rs += __shfl_xor(rs, 16);
      rs += __shfl_xor(rs, 32);
      if (g == 0) rowpart[lrow*WARPS_N + wc] = rs;
    }
    __syncthreads();
    if (t < TM){
      float s2 = 0.f;
      #pragma unroll
      for (int j = 0; j < WARPS_N; j++) s2 += rowpart[t*WARPS_N + j];
      partial[((long long)bz*4096 + m0 + t)*16 + by] = s2;
    }
  } else if constexpr (MODE == 5){
    // fused denominator: dptr = partial [B*4096][16]
    short* outb = (short*)outp + bz*sO;
    #pragma unroll
    for (int mi = 0; mi < MF; mi++){
      int row = m0 + wr*WM + mi*16 + lr;
      const float4* pr = (const float4*)(dptr + (((long long)bz*4096) + row)*16);
      float4 a0 = pr[0], b0 = pr[1], c0 = pr[2], d0 = pr[3];
      float den = a0.x+a0.y+a0.z+a0.w + b0.x+b0.y+b0.z+b0.w
                + c0.x+c0.y+c0.z+c0.w + d0.x+d0.y+d0.z+d0.w;
      float inv = 1.f / den;
      #pragma unroll
      for (int ni = 0; ni < 4; ni++){
        int col = n0 + wc*64 + ni*16 + g*4;
        bf16x4 pk;
        #pragma unroll
        for (int i = 0; i < 4; i++) pk[i] = f2bf(acc[mi][ni][i]*inv);
        *(bf16x4*)&outb[(long long)row*Nn + col] = pk;
      }
    }
  } else if constexpr (MODE == 6){
    const int seg = by >> 2;
    const long long base = (long long)bz*sO;
    short* qp  = (short*)outp;
    short* kp  = (short*)partial;
    short* vtp = (short*)dptr;
    #pragma unroll
    for (int mi = 0; mi < MF; mi++){
      int row = m0 + wr*WM + mi*16 + lr;
      #pragma unroll
      for (int ni = 0; ni < 4; ni++){
        int col = n0 + wc*64 + ni*16 + g*4;
        float4 bb = *(const float4*)&bias[col];
        int cq = col - seg*512;
        float sc = (seg == 0) ? scale : 1.f;
        bf16x4 pk;
        pk[0] = f2bf((acc[mi][ni][0] + bb.x)*sc);
        pk[1] = f2bf((acc[mi][ni][1] + bb.y)*sc);
        pk[2] = f2bf((acc[mi][ni][2] + bb.z)*sc);
        pk[3] = f2bf((acc[mi][ni][3] + bb.w)*sc);
        if (seg == 0)      *(bf16x4*)&qp[base + (long long)row*512 + cq] = pk;
        else if (seg == 1) *(bf16x4*)&kp[base + (long long)row*512 + cq] = pk;
        else {
          #pragma unroll
          for (int i = 0; i < 4; i++)
            vtp[base + (long long)(cq+i)*4096 + row] = pk[i];
        }
      }
    }
  } else {
    float* outb = (float*)outp + bz*sO;
    const float* rx = resid + bz*sO;
    #pragma unroll
    for (int ni = 0; ni < 4; ni++){
      int col = n0 + wc*64 + ni*16 + lr;
      float bv2 = bias[col];
      #pragma unroll
      for (int mi = 0; mi < MF; mi++){
        int row = m0 + wr*WM + mi*16 + g*4;
        long long off = (long long)col*M + row;
        float4 xr = *(const float4*)&rx[off];
        float4 o;
        o.x = acc[mi][ni][0] + bv2 + xr.x;
        o.y = acc[mi][ni][1] + bv2 + xr.y;
        o.z = acc[mi][ni][2] + bv2 + xr.z;
        o.w = acc[mi][ni][3] + bv2 + xr.w;
        *(float4*)&outb[off] = o;
      }
    }
  }
}

extern "C" void kernel_launch(void* const* d_in, const int* in_sizes, int n_in,
                              void* d_out, int out_size, void* d_ws, size_t ws_size,
                              hipStream_t stream)
{
  const float* x   = (const float*)d_in[0];
  const float* gnw = (const float*)d_in[1];
  const float* gnb = (const float*)d_in[2];
  const float* Wq  = (const float*)d_in[3];
  const float* bq  = (const float*)d_in[4];
  const float* Wk  = (const float*)d_in[5];
  const float* bk  = (const float*)d_in[6];
  const float* Wv  = (const float*)d_in[7];
  const float* bvp = (const float*)d_in[8];
  const float* Wo  = (const float*)d_in[9];
  const float* bo  = (const float*)d_in[10];
  float* out = (float*)d_out;

  char* ws = (char*)d_ws;
  const size_t MB = 1ull << 20;
  short* h      = (short*)(ws);
  short* q      = (short*)(ws + 16*MB);
  short* kmat   = (short*)(ws + 32*MB);
  short* vt     = (short*)(ws + 48*MB);
  short* ao     = (short*)(ws + 64*MB);
  short* wqkv   = (short*)(ws + 80*MB);
  short* wob    = wqkv + 3*262144;
  float* stats  = (float*)(ws + 82*MB);
  float* bqkv   = (float*)(ws + 82*MB + 131072);
  float* partial= (float*)(ws + 83*MB);
  short* S      = (short*)(ws + 84*MB);

  const int LDS_8P = 131072;
  const int LDS_SC = 131072;
  const int LDS_QK = 98304;
  const int LDS_PV = 65536;
  hipFuncSetAttribute(reinterpret_cast<const void*>(&gemm8),
                      hipFuncAttributeMaxDynamicSharedMemorySize, LDS_8P);
  hipFuncSetAttribute(reinterpret_cast<const void*>(&gemmF<4,256,256,512,0>),
                      hipFuncAttributeMaxDynamicSharedMemorySize, LDS_SC);
  hipFuncSetAttribute(reinterpret_cast<const void*>(&gemmF<6,256,128,512,0>),
                      hipFuncAttributeMaxDynamicSharedMemorySize, LDS_QK);
  hipFuncSetAttribute(reinterpret_cast<const void*>(&gemmF<5,128,128,256,2>),
                      hipFuncAttributeMaxDynamicSharedMemorySize, LDS_PV);
  hipFuncSetAttribute(reinterpret_cast<const void*>(&gemmF<5,128,128,256,0>),
                      hipFuncAttributeMaxDynamicSharedMemorySize, LDS_PV);
  hipFuncSetAttribute(reinterpret_cast<const void*>(&gemmF<2,128,128,256,0>),
                      hipFuncAttributeMaxDynamicSharedMemorySize, LDS_PV);

  dim3 blk(256);
  dim3 blk512(512);
  gn_stats<<<dim3(128), blk, 0, stream>>>(x, stats);
  gn_apply<<<dim3(64,4), blk, 0, stream>>>(x, stats, gnw, gnb, h);
  f2bf_all<<<dim3(512), blk, 0, stream>>>(Wq, Wk, Wv, Wo,
      wqkv, wqkv + 262144, wqkv + 2*262144, wob, bq, bk, bvp, bqkv);

  const long long sTok = 4096ll*512;
  const long long sS   = 4096ll*4096;
  const float qscale = 0.044194173824159216f;  // 1/sqrt(512)

  gemmF<6,256,128,512,0><<<dim3(16,12,4), blk512, LDS_QK, stream>>>(
      h, wqkv, bqkv, q, nullptr, 4096, 1536, 512, sTok, 0, sTok, qscale,
      (const float*)vt, (float*)kmat);

  if (ws_size >= 212*MB){
    gemm8<<<dim3(1024), blk512, LDS_8P, stream>>>(
        q, kmat, S, 4096, 512, sTok, sTok, sS, partial);
    gemmF<5,128,128,256,2><<<dim3(512), blk, LDS_PV, stream>>>(
        S, vt, nullptr, ao, nullptr, 4096, 512, 4096, sS, sTok, sTok, 1.f, partial, nullptr);
  } else {
    for (int b = 0; b < 4; b++){
      gemmF<4,256,256,512,0><<<dim3(16,16,1), blk512, LDS_SC, stream>>>(
          q + b*sTok, kmat + b*sTok, nullptr, S, nullptr, 4096, 4096, 512, 0, 0, 0, 1.f, nullptr, partial);
      gemmF<5,128,128,256,0><<<dim3(32,4,1), blk, LDS_PV, stream>>>(
          S, vt + b*sTok, nullptr, ao + b*sTok, nullptr, 4096, 512, 4096, 0, 0, 0, 1.f, partial, nullptr);
    }
  }

  gemmF<2,128,128,256,0><<<dim3(32,4,4), blk, LDS_PV, stream>>>(
      ao, wob, bo, out, x, 4096, 512, 512, sTok, 0, sTok, 1.f, nullptr, nullptr);
}